// Round 3
// baseline (264.630 us; speedup 1.0000x reference)
//
#include <hip/hip_runtime.h>
#include <hip/hip_cooperative_groups.h>

namespace cg = cooperative_groups;

#define CC 512
#define CK 256
#define BB 8
#define TT 1024

__device__ __forceinline__ float wave_allreduce(float v) {
#pragma unroll
    for (int m = 1; m < 64; m <<= 1)
        v += __shfl_xor(v, m, 64);
    return v;
}

// One cooperative kernel, 1024 blocks x 256 threads = 4096 waves.
// Wave `wid` owns row (b = wid>>9, c = wid&511) in every phase.
//  P1: v1[b,c] = Wv[c,:]@cond[b,:] + bv[c]          (K=256)
//  P2: v2[b,c] = W2[c,:]@v1[b,:]   + b2[c]          (K=512)
//  P3: u [b,c] = O [c,:]@v2[b,:]   + ob[c]          (K=512)
//  P4: w       = P [c,:]@u [b,:]   + pb[c]  (in-reg), then stream
//      out[b,c,:] = x[b,c,:] + w  (4 KB row, float4)
__global__ void __launch_bounds__(256)
fused_all(const float* __restrict__ x, const float* __restrict__ cond,
          const float* __restrict__ Wv, const float* __restrict__ bv,
          const float* __restrict__ W2, const float* __restrict__ b2,
          const float* __restrict__ O,  const float* __restrict__ ob,
          const float* __restrict__ P,  const float* __restrict__ pb,
          float* __restrict__ v1, float* __restrict__ v2, float* __restrict__ u,
          float* __restrict__ out) {
    cg::grid_group grid = cg::this_grid();
    const int lane = threadIdx.x & 63;
    const int wid = blockIdx.x * 4 + (threadIdx.x >> 6);   // 0..4095
    const int b = wid >> 9, c = wid & 511;

    // P1
    {
        float acc = 0.f;
#pragma unroll
        for (int j = 0; j < CK; j += 64)
            acc += Wv[c * CK + j + lane] * cond[b * CK + j + lane];
        acc = wave_allreduce(acc);
        if (lane == 0) v1[wid] = acc + bv[c];
    }
    grid.sync();

    // P2
    {
        float acc = 0.f;
#pragma unroll
        for (int j = 0; j < CC; j += 64)
            acc += W2[c * CC + j + lane] * v1[b * CC + j + lane];
        acc = wave_allreduce(acc);
        if (lane == 0) v2[wid] = acc + b2[c];
    }
    grid.sync();

    // P3
    {
        float acc = 0.f;
#pragma unroll
        for (int j = 0; j < CC; j += 64)
            acc += O[c * CC + j + lane] * v2[b * CC + j + lane];
        acc = wave_allreduce(acc);
        if (lane == 0) u[wid] = acc + ob[c];
    }
    grid.sync();

    // P4: dot in-register, then stream own row — no further sync.
    {
        float acc = 0.f;
#pragma unroll
        for (int j = 0; j < CC; j += 64)
            acc += P[c * CC + j + lane] * u[b * CC + j + lane];
        const float w = wave_allreduce(acc) + pb[c];

        const float4* x4 = (const float4*)x + (size_t)wid * (TT / 4);
        float4* o4 = (float4*)out + (size_t)wid * (TT / 4);
#pragma unroll
        for (int i = 0; i < TT / 4; i += 64) {
            float4 vv = x4[i + lane];
            vv.x += w; vv.y += w; vv.z += w; vv.w += w;
            o4[i + lane] = vv;
        }
    }
}

extern "C" void kernel_launch(void* const* d_in, const int* in_sizes, int n_in,
                              void* d_out, int out_size, void* d_ws, size_t ws_size,
                              hipStream_t stream) {
    const float* x    = (const float*)d_in[0];
    const float* cond = (const float*)d_in[1];
    const float* Wv   = (const float*)d_in[8];
    const float* bv   = (const float*)d_in[9];
    const float* W2   = (const float*)d_in[10] + 2 * CC * CC;  // in_proj_w rows [2C,3C)
    const float* b2   = (const float*)d_in[11] + 2 * CC;       // in_proj_b[2C:]
    const float* O    = (const float*)d_in[12];
    const float* ob   = (const float*)d_in[13];
    const float* P    = (const float*)d_in[14];
    const float* pb   = (const float*)d_in[15];
    float* out = (float*)d_out;

    float* v1 = (float*)d_ws;
    float* v2 = v1 + BB * CC;
    float* u  = v2 + BB * CC;

    void* args[] = { (void*)&x, (void*)&cond, (void*)&Wv, (void*)&bv,
                     (void*)&W2, (void*)&b2, (void*)&O, (void*)&ob,
                     (void*)&P, (void*)&pb, (void*)&v1, (void*)&v2, (void*)&u,
                     (void*)&out };
    hipLaunchCooperativeKernel((const void*)fused_all, dim3(1024), dim3(256),
                               args, 0, stream);
}

// Round 4
// 80.968 us; speedup vs baseline: 3.2683x; 3.2683x over previous
//
#include <hip/hip_runtime.h>

#define CC 512
#define CK 256
#define BB 8
#define TT 1024
#define NBLK 512
#define NTHR 512

__device__ __forceinline__ float wave_allreduce(float v) {
#pragma unroll
    for (int m = 1; m < 64; m <<= 1) v += __shfl_xor(v, m, 64);
    return v;
}

// Hand-rolled grid barrier:
//  arrive: tid0 release-stores 1 into this block's slot (after __syncthreads,
//          whose per-wave vmcnt drain makes prior agent-stores visible at L3).
//  wait:   thread t polls slot[k][t] (NTHR==NBLK, one slot each), relaxed + sleep.
#define ARRIVE(k)                                                               \
    __syncthreads();                                                            \
    if (tid == 0)                                                               \
        __hip_atomic_store(&slots[(k)*NBLK + blockIdx.x], 1u,                   \
                           __ATOMIC_RELEASE, __HIP_MEMORY_SCOPE_AGENT);

#define WAITBAR(k)                                                              \
    {                                                                           \
        unsigned* _sp = &slots[(k)*NBLK + tid];                                 \
        while (__hip_atomic_load(_sp, __ATOMIC_RELAXED,                         \
                                 __HIP_MEMORY_SCOPE_AGENT) == 0u)               \
            __builtin_amdgcn_s_sleep(1);                                        \
        __syncthreads();                                                        \
    }

__global__ void __launch_bounds__(NTHR, 4)
fused(const float* __restrict__ x, const float* __restrict__ cond,
      const float* __restrict__ Wv, const float* __restrict__ bv,
      const float* __restrict__ W2, const float* __restrict__ b2,
      const float* __restrict__ O,  const float* __restrict__ ob,
      const float* __restrict__ P,  const float* __restrict__ pb,
      float* __restrict__ v1, float* __restrict__ v2, float* __restrict__ u,
      unsigned* __restrict__ slots, float* __restrict__ out)
{
    const int tid = threadIdx.x;
    const int lane = tid & 63;
    const int wid = blockIdx.x * (NTHR / 64) + (tid >> 6);  // 0..4095
    const int b = wid >> 9, c = wid & 511;

    // ---- P1: v1[b,c] = Wv[c,:]@cond[b,:] + bv[c]   (K=256)
    {
        float acc = 0.f;
#pragma unroll
        for (int j = 0; j < CK; j += 64)
            acc += Wv[c * CK + j + lane] * cond[b * CK + j + lane];
        acc = wave_allreduce(acc);
        if (lane == 0)
            __hip_atomic_store(&v1[wid], acc + bv[c], __ATOMIC_RELAXED,
                               __HIP_MEMORY_SCOPE_AGENT);
    }
    ARRIVE(0);
    // prefetch W2 row while others arrive
    float wr[8];
#pragma unroll
    for (int i = 0; i < 8; ++i) wr[i] = W2[c * CC + i * 64 + lane];
    float bias = b2[c];
    WAITBAR(0);

    // ---- P2: v2[b,c] = W2[c,:]@v1[b,:] + b2[c]   (K=512)
    {
        float acc = 0.f;
#pragma unroll
        for (int i = 0; i < 8; ++i) {
            float vv = __hip_atomic_load(&v1[b * CC + i * 64 + lane],
                                         __ATOMIC_RELAXED, __HIP_MEMORY_SCOPE_AGENT);
            acc += wr[i] * vv;
        }
        acc = wave_allreduce(acc);
        if (lane == 0)
            __hip_atomic_store(&v2[wid], acc + bias, __ATOMIC_RELAXED,
                               __HIP_MEMORY_SCOPE_AGENT);
    }
    ARRIVE(1);
#pragma unroll
    for (int i = 0; i < 8; ++i) wr[i] = O[c * CC + i * 64 + lane];
    bias = ob[c];
    WAITBAR(1);

    // ---- P3: u[b,c] = O[c,:]@v2[b,:] + ob[c]   (K=512)
    {
        float acc = 0.f;
#pragma unroll
        for (int i = 0; i < 8; ++i) {
            float vv = __hip_atomic_load(&v2[b * CC + i * 64 + lane],
                                         __ATOMIC_RELAXED, __HIP_MEMORY_SCOPE_AGENT);
            acc += wr[i] * vv;
        }
        acc = wave_allreduce(acc);
        if (lane == 0)
            __hip_atomic_store(&u[wid], acc + bias, __ATOMIC_RELAXED,
                               __HIP_MEMORY_SCOPE_AGENT);
    }
    ARRIVE(2);
    // prefetch P row, pb, and this wave's whole 4KB x-chunk while others arrive
#pragma unroll
    for (int i = 0; i < 8; ++i) wr[i] = P[c * CC + i * 64 + lane];
    bias = pb[c];
    float4 xr[4];
    const float4* x4 = (const float4*)x + (size_t)wid * (TT / 4);
#pragma unroll
    for (int i = 0; i < 4; ++i) xr[i] = x4[i * 64 + lane];
    WAITBAR(2);

    // ---- P4: w = P[c,:]@u[b,:] + pb[c]; out[b,c,:] = x[b,c,:] + w
    {
        float acc = 0.f;
#pragma unroll
        for (int i = 0; i < 8; ++i) {
            float uv = __hip_atomic_load(&u[b * CC + i * 64 + lane],
                                         __ATOMIC_RELAXED, __HIP_MEMORY_SCOPE_AGENT);
            acc += wr[i] * uv;
        }
        const float w = wave_allreduce(acc) + bias;
        float4* o4 = (float4*)out + (size_t)wid * (TT / 4);
#pragma unroll
        for (int i = 0; i < 4; ++i) {
            float4 vv = xr[i];
            vv.x += w; vv.y += w; vv.z += w; vv.w += w;
            o4[i * 64 + lane] = vv;
        }
    }
}

extern "C" void kernel_launch(void* const* d_in, const int* in_sizes, int n_in,
                              void* d_out, int out_size, void* d_ws, size_t ws_size,
                              hipStream_t stream) {
    const float* x    = (const float*)d_in[0];
    const float* cond = (const float*)d_in[1];
    const float* Wv   = (const float*)d_in[8];
    const float* bv   = (const float*)d_in[9];
    const float* W2   = (const float*)d_in[10] + 2 * CC * CC;  // in_proj_w rows [2C,3C)
    const float* b2   = (const float*)d_in[11] + 2 * CC;
    const float* O    = (const float*)d_in[12];
    const float* ob   = (const float*)d_in[13];
    const float* P    = (const float*)d_in[14];
    const float* pb   = (const float*)d_in[15];
    float* out = (float*)d_out;

    float* v1 = (float*)d_ws;                 // 4096 f
    float* v2 = v1 + BB * CC;                 // 4096 f
    float* u  = v2 + BB * CC;                 // 4096 f
    unsigned* slots = (unsigned*)(u + BB * CC);  // 3*512 u32

    hipMemsetAsync(slots, 0, 3 * NBLK * sizeof(unsigned), stream);

    void* args[] = { (void*)&x, (void*)&cond, (void*)&Wv, (void*)&bv,
                     (void*)&W2, (void*)&b2, (void*)&O, (void*)&ob,
                     (void*)&P, (void*)&pb, (void*)&v1, (void*)&v2, (void*)&u,
                     (void*)&slots, (void*)&out };
    hipLaunchCooperativeKernel((const void*)fused, dim3(NBLK), dim3(NTHR),
                               args, 0, stream);
}

// Round 5
// 25.675 us; speedup vs baseline: 10.3069x; 3.1535x over previous
//
#include <hip/hip_runtime.h>

#define CC 512
#define CK 256
#define BB 8
#define TT 1024
#define MAGIC1 0x517E0001u
#define MAGIC2 0x517E0002u

__device__ __forceinline__ float wave_allreduce(float v) {
#pragma unroll
    for (int m = 1; m < 64; m <<= 1) v += __shfl_xor(v, m, 64);
    return v;
}
__device__ __forceinline__ float dot4(float4 a, float4 b) {
    return a.x * b.x + a.y * b.y + a.z * b.z + a.w * b.w;
}

// D1: v1 -> v2 -> u chain. 64 blocks x 512 threads; wave g owns column c=g.
// Cross-block sync via relaxed flag barrier (NO release -> no buffer_wbl2).
__global__ void __launch_bounds__(512)
chain_kernel(const float* __restrict__ cond,
             const float* __restrict__ Wv, const float* __restrict__ bv,
             const float* __restrict__ W2, const float* __restrict__ b2,
             const float* __restrict__ O,  const float* __restrict__ ob,
             float* __restrict__ v1g, float* __restrict__ v2g,
             float* __restrict__ u, unsigned* __restrict__ slots)
{
    __shared__ float lds[BB * CC];               // 16 KB
    const int tid  = threadIdx.x;
    const int lane = tid & 63;
    const int c    = blockIdx.x * 8 + (tid >> 6);  // 0..511
    float accs[BB];

    // ---- P1: v1[b,c] = Wv[c,:]@cond[b,:] + bv[c]   (K=256)
    const float4 wv4 = *(const float4*)&Wv[c * CK + lane * 4];
    const float bvc = bv[c];
#pragma unroll
    for (int b = 0; b < BB; ++b)
        accs[b] = dot4(wv4, *(const float4*)&cond[b * CK + lane * 4]);
#pragma unroll
    for (int b = 0; b < BB; ++b) {
        const float r = wave_allreduce(accs[b]);
        if (lane == 0)
            __hip_atomic_store(&v1g[b * CC + c], r + bvc, __ATOMIC_RELAXED,
                               __HIP_MEMORY_SCOPE_AGENT);
    }
    // barrier 0 arrive: syncthreads drains vmcnt per wave; sc1 stores are at
    // the coherent point when vmcnt retires -> relaxed flag store suffices.
    __syncthreads();
    if (tid == 0) {
        asm volatile("s_waitcnt vmcnt(0)" ::: "memory");
        __hip_atomic_store(&slots[blockIdx.x], MAGIC1, __ATOMIC_RELAXED,
                           __HIP_MEMORY_SCOPE_AGENT);
    }
    // prefetch W2 row while polling
    const float4 w2a = *(const float4*)&W2[c * CC + lane * 4];
    const float4 w2b = *(const float4*)&W2[c * CC + CK + lane * 4];
    const float b2c = b2[c];
    {
        unsigned* sp = &slots[tid & 63];
        while (__hip_atomic_load(sp, __ATOMIC_RELAXED,
                                 __HIP_MEMORY_SCOPE_AGENT) != MAGIC1)
            __builtin_amdgcn_s_sleep(1);
    }
    asm volatile("" ::: "memory");
    // stage v1 -> LDS (16 KB, coalesced float4)
    {
        const float4* g4 = (const float4*)v1g;
        float4* l4 = (float4*)lds;
        l4[tid * 2] = g4[tid * 2];
        l4[tid * 2 + 1] = g4[tid * 2 + 1];
    }
    __syncthreads();

    // ---- P2: v2[b,c] = W2[c,:]@v1[b,:] + b2[c]   (K=512)
#pragma unroll
    for (int b = 0; b < BB; ++b)
        accs[b] = dot4(w2a, *(const float4*)&lds[b * CC + lane * 4]) +
                  dot4(w2b, *(const float4*)&lds[b * CC + CK + lane * 4]);
#pragma unroll
    for (int b = 0; b < BB; ++b) {
        const float r = wave_allreduce(accs[b]);
        if (lane == 0)
            __hip_atomic_store(&v2g[b * CC + c], r + b2c, __ATOMIC_RELAXED,
                               __HIP_MEMORY_SCOPE_AGENT);
    }
    __syncthreads();
    if (tid == 0) {
        asm volatile("s_waitcnt vmcnt(0)" ::: "memory");
        __hip_atomic_store(&slots[64 + blockIdx.x], MAGIC2, __ATOMIC_RELAXED,
                           __HIP_MEMORY_SCOPE_AGENT);
    }
    const float4 oa = *(const float4*)&O[c * CC + lane * 4];
    const float4 oc = *(const float4*)&O[c * CC + CK + lane * 4];
    const float obc = ob[c];
    {
        unsigned* sp = &slots[64 + (tid & 63)];
        while (__hip_atomic_load(sp, __ATOMIC_RELAXED,
                                 __HIP_MEMORY_SCOPE_AGENT) != MAGIC2)
            __builtin_amdgcn_s_sleep(1);
    }
    asm volatile("" ::: "memory");
    {
        const float4* g4 = (const float4*)v2g;
        float4* l4 = (float4*)lds;
        l4[tid * 2] = g4[tid * 2];
        l4[tid * 2 + 1] = g4[tid * 2 + 1];
    }
    __syncthreads();

    // ---- P3: u[b,c] = O[c,:]@v2[b,:] + ob[c]  (plain store; dispatch-end fence)
#pragma unroll
    for (int b = 0; b < BB; ++b)
        accs[b] = dot4(oa, *(const float4*)&lds[b * CC + lane * 4]) +
                  dot4(oc, *(const float4*)&lds[b * CC + CK + lane * 4]);
#pragma unroll
    for (int b = 0; b < BB; ++b) {
        const float r = wave_allreduce(accs[b]);
        if (lane == 0) u[b * CC + c] = r + obc;
    }
}

// D2: wave per (b,c) row: w = P[c,:]@u[b,:] + pb[c]; out row = x row + w.
// Also resets the flag slots for the next graph replay.
__global__ void __launch_bounds__(256)
stream_kernel(const float* __restrict__ x, const float* __restrict__ P,
              const float* __restrict__ pb, const float* __restrict__ u,
              unsigned* __restrict__ slots, float* __restrict__ out)
{
    const int tid = threadIdx.x;
    const int lane = tid & 63;
    const int row = blockIdx.x * 4 + (tid >> 6);   // 0..4095
    const int b = row >> 9, c = row & 511;
    if (blockIdx.x == 0 && tid < 128) slots[tid] = 0;

    const float4 pa = *(const float4*)&P[c * CC + lane * 4];
    const float4 pc = *(const float4*)&P[c * CC + CK + lane * 4];
    const float4 ua = *(const float4*)&u[b * CC + lane * 4];
    const float4 ub = *(const float4*)&u[b * CC + CK + lane * 4];
    const float w = wave_allreduce(dot4(pa, ua) + dot4(pc, ub)) + pb[c];

    const float4* x4 = (const float4*)x + (size_t)row * (TT / 4);
    float4* o4 = (float4*)out + (size_t)row * (TT / 4);
#pragma unroll
    for (int i = 0; i < 4; ++i) {
        float4 v = x4[i * 64 + lane];
        v.x += w; v.y += w; v.z += w; v.w += w;
        o4[i * 64 + lane] = v;
    }
}

extern "C" void kernel_launch(void* const* d_in, const int* in_sizes, int n_in,
                              void* d_out, int out_size, void* d_ws, size_t ws_size,
                              hipStream_t stream) {
    const float* x    = (const float*)d_in[0];
    const float* cond = (const float*)d_in[1];
    const float* Wv   = (const float*)d_in[8];
    const float* bv   = (const float*)d_in[9];
    const float* W2   = (const float*)d_in[10] + 2 * CC * CC;  // in_proj_w rows [2C,3C)
    const float* b2   = (const float*)d_in[11] + 2 * CC;
    const float* O    = (const float*)d_in[12];
    const float* ob   = (const float*)d_in[13];
    const float* P    = (const float*)d_in[14];
    const float* pb   = (const float*)d_in[15];
    float* out = (float*)d_out;

    float* v1g = (float*)d_ws;                    // 4096 f
    float* v2g = v1g + BB * CC;                   // 4096 f
    float* u   = v2g + BB * CC;                   // 4096 f
    unsigned* slots = (unsigned*)(u + BB * CC);   // 128 u32

    chain_kernel<<<64, 512, 0, stream>>>(cond, Wv, bv, W2, b2, O, ob,
                                         v1g, v2g, u, slots);
    stream_kernel<<<1024, 256, 0, stream>>>(x, P, pb, u, slots, out);
}